// Round 4
// baseline (243.134 us; speedup 1.0000x reference)
//
#include <hip/hip_runtime.h>
#include <hip/hip_bf16.h>
#include <hip/hip_fp8.h>

#define VOCAB  100000
#define EMB    128
#define NCODES 100000
#define NANC   8

typedef __attribute__((ext_vector_type(8))) short  short8;
typedef __attribute__((ext_vector_type(4))) float  float4v;
typedef __attribute__((ext_vector_type(2))) float  floatx2;

__device__ __forceinline__ ushort f2bf(float x) {     // RNE f32 -> bf16 bits
    unsigned u = __float_as_uint(x);
    u += 0x7fffu + ((u >> 16) & 1u);
    return (ushort)(u >> 16);
}
__device__ __forceinline__ float bf2f(ushort h) {
    return __uint_as_float((unsigned)h << 16);
}
__device__ __forceinline__ float tanh_fast(float x) {
    float e = __expf(2.0f * x);               // saturates correctly at +-inf
    return 1.0f - __fdividef(2.0f, e + 1.0f);
}
__device__ __forceinline__ unsigned char f2fp8(float x) {  // OCP e4m3, RNE+sat
    __hip_fp8_e4m3 t(x);
    return t.__x;
}
// decode 2 fp8 from the low/high 16-bit word of v (HI must be compile-time)
template <bool HI>
__device__ __forceinline__ floatx2 fp8pair(unsigned v) {
#if __has_builtin(__builtin_amdgcn_cvt_pk_f32_fp8)
    return __builtin_amdgcn_cvt_pk_f32_fp8((int)v, HI);
#else
    __hip_fp8_e4m3 a, b;
    const unsigned s = HI ? 16u : 0u;
    a.__x = (v >> s) & 0xffu;
    b.__x = (v >> (s + 8u)) & 0xffu;
    floatx2 r; r[0] = (float)a; r[1] = (float)b; return r;
#endif
}

// ---------------------------------------------------------------------------
// Kernel A0: WT[c][e] = bf16(W_att[h*128+e][d]), c = h*128+d.  64 KB output;
// scattered 4B reads are fully L2-absorbed (131 KB input). ~2-3 us.
// ---------------------------------------------------------------------------
__global__ void transpose_watt(const float* __restrict__ W_att,
                               ushort* __restrict__ WT)
{
    const int id = blockIdx.x * 256 + threadIdx.x;   // 32768 total
    const int c = id >> 7, e = id & 127;
    const int h = c >> 7, d = c & 127;
    WT[c * 128 + e] = f2bf(W_att[(h * 128 + e) * 128 + d]);
}

// ---------------------------------------------------------------------------
// Kernel A: LDS-free MFMA precompute.  Block = 16 rows x 256 cols; wave w
// covers cols w*64..w*64+63 with its 16 B-frags held in registers (loaded
// from L2-resident WT).  P1 = rows@W1 + b (fp8), P2 = rows@W2 (fp8),
// Ebf = bf16(W_emb) emitted by wave 0 from the shared A-fragments.
// ---------------------------------------------------------------------------
__global__ __launch_bounds__(256) void precompute(
    const float*  __restrict__ W_emb,   // [VOCAB][128] f32
    const ushort* __restrict__ WT,      // [256][128] bf16 (A0 output)
    const float*  __restrict__ b_att,   // [128]
    unsigned char* __restrict__ P1,     // [VOCAB][128] fp8
    unsigned char* __restrict__ P2,     // [VOCAB][128] fp8
    ushort*        __restrict__ Ebf)    // [VOCAB][128] bf16
{
    const int t = threadIdx.x, wave = t >> 6, lane = t & 63;
    const int n15 = lane & 15, quad = lane >> 4;
    const int R = blockIdx.x * 16;                     // 6250 * 16 = VOCAB exact

    // B-frags in registers: B[k=quad*8+j][n] = WT[c][kt*32+quad*8+j]
    short8 bfrag[4][4];                                // [kt][ntl]
    #pragma unroll
    for (int ntl = 0; ntl < 4; ++ntl) {
        const int c = wave * 64 + ntl * 16 + n15;
        #pragma unroll
        for (int kt = 0; kt < 4; ++kt)
            bfrag[kt][ntl] = *(const short8*)(WT + c * 128 + kt * 32 + quad * 8);
    }

    float4v acc[4];
    #pragma unroll
    for (int i = 0; i < 4; ++i) acc[i] = (float4v)0.0f;

    #pragma unroll
    for (int kt = 0; kt < 4; ++kt) {
        // A-frag: A[m=lane&15][k=quad*8+j]
        const float4* src = (const float4*)(W_emb + (size_t)(R + n15) * 128
                                            + kt * 32 + quad * 8);
        const float4 a0 = src[0], a1 = src[1];
        short8 af;
        af[0] = f2bf(a0.x); af[1] = f2bf(a0.y); af[2] = f2bf(a0.z); af[3] = f2bf(a0.w);
        af[4] = f2bf(a1.x); af[5] = f2bf(a1.y); af[6] = f2bf(a1.z); af[7] = f2bf(a1.w);
        if (wave == 0)    // free bf16 W_emb copy (16 rows x 128 cols per block)
            __builtin_nontemporal_store(af,
                (short8*)(Ebf + (size_t)(R + n15) * 128 + kt * 32 + quad * 8));
        #pragma unroll
        for (int ntl = 0; ntl < 4; ++ntl)
            acc[ntl] = __builtin_amdgcn_mfma_f32_16x16x32_bf16(
                           af, bfrag[kt][ntl], acc[ntl], 0, 0, 0);
    }

    // Epilogue. C/D: col = lane&15 (+16*ntl), row = quad*4 + reg.
    const int cw = wave * 64;
    float bv[4] = {0.f, 0.f, 0.f, 0.f};
    if (wave < 2) {
        #pragma unroll
        for (int ntl = 0; ntl < 4; ++ntl) bv[ntl] = b_att[cw + ntl * 16 + n15];
    }
    unsigned char* Pt = (wave < 2) ? P1 : P2;
    const int cofs = (wave < 2) ? cw : cw - 128;
    #pragma unroll
    for (int ntl = 0; ntl < 4; ++ntl) {
        const int c = cofs + ntl * 16 + n15;
        #pragma unroll
        for (int i = 0; i < 4; ++i) {
            const int r = R + quad * 4 + i;
            __builtin_nontemporal_store(f2fp8(acc[ntl][i] + bv[ntl]),
                                        Pt + (size_t)r * 128 + c);
        }
    }
}

// ---------------------------------------------------------------------------
// Kernel B: 16 lanes per code, 4 codes per wave.  Lane owns 8 cols.
// Gathers: P1[leaf] 8B fp8, P2[anc] 8B fp8, Ebf[anc] 16B bf16.
// Folded butterfly (8 shuffles) -> q[a] at lane group a = (b3,b2,b1);
// distributed softmax (1 exp/lane); shuffle-broadcast of 8 weights.
// ---------------------------------------------------------------------------
__global__ __launch_bounds__(256) void attention_main(
    const unsigned char* __restrict__ P1, const unsigned char* __restrict__ P2,
    const ushort* __restrict__ Ebf,
    const float* __restrict__ v_att,
    const int*   __restrict__ leaves, const int* __restrict__ anc,
    float*       __restrict__ out)
{
    const int t = threadIdx.x;
    const int wave = t >> 6, lane = t & 63;
    const int sub = lane >> 4, l16 = lane & 15;
    const int n = blockIdx.x * 16 + wave * 4 + sub;    // 6250*16 = NCODES exact

    const float4 vva = *(const float4*)(v_att + l16 * 8);
    const float4 vvb = *(const float4*)(v_att + l16 * 8 + 4);

    // distributed index load: lane j=l16<8 -> leaf j, j>=8 -> anc j-8
    const int jj = l16 & 7;
    const int lidx = (l16 & 8) ? anc[n * 8 + jj] : leaves[n * 8 + jj];

    short8 em[NANC];
    float q[NANC];
    #pragma unroll
    for (int a = 0; a < NANC; ++a) {
        const int lf = __shfl(lidx, (sub << 4) + a);
        const int an = __shfl(lidx, (sub << 4) + 8 + a);
        const uint2 r1 = *(const uint2*)(P1 + (size_t)lf * 128 + l16 * 8);
        const uint2 r2 = *(const uint2*)(P2 + (size_t)an * 128 + l16 * 8);
        em[a] = *(const short8*)(Ebf + (size_t)an * 128 + l16 * 8);
        floatx2 pa, pb;
        float qp;
        pa = fp8pair<false>(r1.x); pb = fp8pair<false>(r2.x);
        qp  = tanh_fast(pa[0] + pb[0]) * vva.x;
        qp  = fmaf(tanh_fast(pa[1] + pb[1]), vva.y, qp);
        pa = fp8pair<true>(r1.x);  pb = fp8pair<true>(r2.x);
        qp  = fmaf(tanh_fast(pa[0] + pb[0]), vva.z, qp);
        qp  = fmaf(tanh_fast(pa[1] + pb[1]), vva.w, qp);
        pa = fp8pair<false>(r1.y); pb = fp8pair<false>(r2.y);
        qp  = fmaf(tanh_fast(pa[0] + pb[0]), vvb.x, qp);
        qp  = fmaf(tanh_fast(pa[1] + pb[1]), vvb.y, qp);
        pa = fp8pair<true>(r1.y);  pb = fp8pair<true>(r2.y);
        qp  = fmaf(tanh_fast(pa[0] + pb[0]), vvb.z, qp);
        qp  = fmaf(tanh_fast(pa[1] + pb[1]), vvb.w, qp);
        q[a] = qp;
    }

    // Folded reduction over 16 lanes: a-bit2<-l-bit3, bit1<-l-bit2, bit0<-l-bit1
    float r4[4];
    #pragma unroll
    for (int i = 0; i < 4; ++i) {
        const float keep = (l16 & 8) ? q[i + 4] : q[i];
        const float send = (l16 & 8) ? q[i]     : q[i + 4];
        r4[i] = keep + __shfl_xor(send, 8);
    }
    float s2[2];
    #pragma unroll
    for (int i = 0; i < 2; ++i) {
        const float keep = (l16 & 4) ? r4[i + 2] : r4[i];
        const float send = (l16 & 4) ? r4[i]     : r4[i + 2];
        s2[i] = keep + __shfl_xor(send, 4);
    }
    {
        const float keep = (l16 & 2) ? s2[1] : s2[0];
        const float send = (l16 & 2) ? s2[0] : s2[1];
        s2[0] = keep + __shfl_xor(send, 2);
    }
    float tq = s2[0] + __shfl_xor(s2[0], 1);   // lane holds q_total[A(l)]

    // distributed softmax over the 8 a-groups (lane bits 3,2,1)
    float m = tq;
    m = fmaxf(m, __shfl_xor(m, 8));
    m = fmaxf(m, __shfl_xor(m, 4));
    m = fmaxf(m, __shfl_xor(m, 2));
    const float e = __expf(tq - m);
    float s = e;
    s += __shfl_xor(s, 8); s += __shfl_xor(s, 4); s += __shfl_xor(s, 2);
    const float wl = e * __fdividef(1.0f, s);

    // broadcast the 8 weights to every lane
    float wa[NANC];
    {
        const float p  = __shfl_xor(wl, 2);
        const float w0 = (l16 & 2) ? p  : wl;   // a-bit0 = 0
        const float w1 = (l16 & 2) ? wl : p;    // a-bit0 = 1
        const float p0 = __shfl_xor(w0, 4), p1 = __shfl_xor(w1, 4);
        const float v00 = (l16 & 4) ? p0 : w0, v01 = (l16 & 4) ? p1 : w1;
        const float v10 = (l16 & 4) ? w0 : p0, v11 = (l16 & 4) ? w1 : p1;
        float g;
        g = __shfl_xor(v00, 8); wa[0] = (l16 & 8) ? g : v00; wa[4] = (l16 & 8) ? v00 : g;
        g = __shfl_xor(v01, 8); wa[1] = (l16 & 8) ? g : v01; wa[5] = (l16 & 8) ? v01 : g;
        g = __shfl_xor(v10, 8); wa[2] = (l16 & 8) ? g : v10; wa[6] = (l16 & 8) ? v10 : g;
        g = __shfl_xor(v11, 8); wa[3] = (l16 & 8) ? g : v11; wa[7] = (l16 & 8) ? v11 : g;
    }

    float o[8] = {0.f, 0.f, 0.f, 0.f, 0.f, 0.f, 0.f, 0.f};
    #pragma unroll
    for (int a = 0; a < NANC; ++a) {
        #pragma unroll
        for (int c = 0; c < 8; ++c)
            o[c] = fmaf(wa[a], bf2f((ushort)em[a][c]), o[c]);
    }
    float4v o1, o2;
    o1[0] = o[0]; o1[1] = o[1]; o1[2] = o[2]; o1[3] = o[3];
    o2[0] = o[4]; o2[1] = o[5]; o2[2] = o[6]; o2[3] = o[7];
    __builtin_nontemporal_store(o1, (float4v*)(out + (size_t)n * 128 + l16 * 8));
    __builtin_nontemporal_store(o2, (float4v*)(out + (size_t)n * 128 + l16 * 8 + 4));
}

// ---------------------------------------------------------------------------
extern "C" void kernel_launch(void* const* d_in, const int* in_sizes, int n_in,
                              void* d_out, int out_size, void* d_ws, size_t ws_size,
                              hipStream_t stream) {
    const float* W_emb  = (const float*)d_in[0];
    const float* W_att  = (const float*)d_in[1];
    const float* b_att  = (const float*)d_in[2];
    const float* v_att  = (const float*)d_in[3];
    const int*   leaves = (const int*)d_in[4];
    const int*   anc    = (const int*)d_in[5];
    float*       out    = (float*)d_out;

    unsigned char* P1 = (unsigned char*)d_ws;            // 12.8 MB fp8
    unsigned char* P2 = P1 + (size_t)VOCAB * 128;        // 12.8 MB fp8
    ushort* Ebf = (ushort*)(P2 + (size_t)VOCAB * 128);   // 25.6 MB bf16
    ushort* WT  = Ebf + (size_t)VOCAB * 128;             // 64 KB bf16

    transpose_watt<<<128, 256, 0, stream>>>(W_att, WT);
    precompute<<<VOCAB / 16, 256, 0, stream>>>(W_emb, WT, b_att, P1, P2, Ebf);
    attention_main<<<NCODES / 16, 256, 0, stream>>>(P1, P2, Ebf, v_att,
                                                    leaves, anc, out);
}

// Round 5
// 230.982 us; speedup vs baseline: 1.0526x; 1.0526x over previous
//
#include <hip/hip_runtime.h>
#include <hip/hip_bf16.h>
#include <hip/hip_fp8.h>

#define VOCAB  100000
#define EMB    128
#define NCODES 100000
#define NANC   8

typedef __attribute__((ext_vector_type(8))) short  short8;
typedef __attribute__((ext_vector_type(4))) float  float4v;
typedef __attribute__((ext_vector_type(4))) unsigned int uint4v;
typedef __attribute__((ext_vector_type(2))) float  floatx2;

__device__ __forceinline__ ushort f2bf(float x) {     // RNE f32 -> bf16 bits
    unsigned u = __float_as_uint(x);
    u += 0x7fffu + ((u >> 16) & 1u);
    return (ushort)(u >> 16);
}
__device__ __forceinline__ float bf2f(ushort h) {
    return __uint_as_float((unsigned)h << 16);
}
__device__ __forceinline__ float tanh_fast(float x) {
    float e = __expf(2.0f * x);               // saturates correctly at +-inf
    return 1.0f - __fdividef(2.0f, e + 1.0f);
}
__device__ __forceinline__ unsigned char f2fp8(float x) {  // OCP e4m3, RNE+sat
    __hip_fp8_e4m3 t(x);
    return t.__x;
}
// decode 2 fp8 from the low/high 16-bit word of v (HI must be compile-time)
template <bool HI>
__device__ __forceinline__ floatx2 fp8pair(unsigned v) {
#if __has_builtin(__builtin_amdgcn_cvt_pk_f32_fp8)
    return __builtin_amdgcn_cvt_pk_f32_fp8((int)v, HI);
#else
    __hip_fp8_e4m3 a, b;
    const unsigned s = HI ? 16u : 0u;
    a.__x = (v >> s) & 0xffu;
    b.__x = (v >> (s + 8u)) & 0xffu;
    floatx2 r; r[0] = (float)a; r[1] = (float)b; return r;
#endif
}

// ---------------------------------------------------------------------------
// Kernel A0: WT[c][e] = bf16(W_att[h*128+e][d]), c = h*128+d.  64 KB output.
// ---------------------------------------------------------------------------
__global__ void transpose_watt(const float* __restrict__ W_att,
                               ushort* __restrict__ WT)
{
    const int id = blockIdx.x * 256 + threadIdx.x;   // 32768 total
    const int c = id >> 7, e = id & 127;
    const int h = c >> 7, d = c & 127;
    WT[c * 128 + e] = f2bf(W_att[(h * 128 + e) * 128 + d]);
}

// ---------------------------------------------------------------------------
// Kernel A: LDS-free-mainloop MFMA precompute.  Block = 16 rows x 256 cols;
// wave w covers cols w*64..w*64+63 (B-frags in registers from L2-resident WT).
// Epilogue: fp8 tile bounced through a 1 KB/wave LDS slice so the global
// store is one coalesced dwordx4 per lane (full 64-B sectors), instead of
// 16 scattered byte stores (R4: 4x write amplification, 132 MB vs 51 MB).
// No nontemporal hints: P1/P2/Ebf are re-read immediately by kernel B.
// ---------------------------------------------------------------------------
__global__ __launch_bounds__(256) void precompute(
    const float*  __restrict__ W_emb,   // [VOCAB][128] f32
    const ushort* __restrict__ WT,      // [256][128] bf16 (A0 output)
    const float*  __restrict__ b_att,   // [128]
    unsigned char* __restrict__ P1,     // [VOCAB][128] fp8
    unsigned char* __restrict__ P2,     // [VOCAB][128] fp8
    ushort*        __restrict__ Ebf)    // [VOCAB][128] bf16
{
    __shared__ __align__(16) unsigned char sP[4][16][64];   // 4 KB

    const int t = threadIdx.x, wave = t >> 6, lane = t & 63;
    const int n15 = lane & 15, quad = lane >> 4;
    const int R = blockIdx.x * 16;                     // 6250 * 16 = VOCAB exact

    // B-frags in registers: B[k=quad*8+j][n] = WT[c][kt*32+quad*8+j]
    short8 bfrag[4][4];                                // [kt][ntl]
    #pragma unroll
    for (int ntl = 0; ntl < 4; ++ntl) {
        const int c = wave * 64 + ntl * 16 + n15;
        #pragma unroll
        for (int kt = 0; kt < 4; ++kt)
            bfrag[kt][ntl] = *(const short8*)(WT + c * 128 + kt * 32 + quad * 8);
    }

    float4v acc[4];
    #pragma unroll
    for (int i = 0; i < 4; ++i) acc[i] = (float4v)0.0f;

    #pragma unroll
    for (int kt = 0; kt < 4; ++kt) {
        // A-frag: A[m=lane&15][k=quad*8+j]
        const float4* src = (const float4*)(W_emb + (size_t)(R + n15) * 128
                                            + kt * 32 + quad * 8);
        const float4 a0 = src[0], a1 = src[1];
        short8 af;
        af[0] = f2bf(a0.x); af[1] = f2bf(a0.y); af[2] = f2bf(a0.z); af[3] = f2bf(a0.w);
        af[4] = f2bf(a1.x); af[5] = f2bf(a1.y); af[6] = f2bf(a1.z); af[7] = f2bf(a1.w);
        if (wave == 0)    // bf16 W_emb copy; 4 quads cover each row's 64B sector
            *(short8*)(Ebf + (size_t)(R + n15) * 128 + kt * 32 + quad * 8) = af;
        #pragma unroll
        for (int ntl = 0; ntl < 4; ++ntl)
            acc[ntl] = __builtin_amdgcn_mfma_f32_16x16x32_bf16(
                           af, bfrag[kt][ntl], acc[ntl], 0, 0, 0);
    }

    // Epilogue. C/D: col = lane&15 (+16*ntl), row = quad*4 + reg.
    const int cw = wave * 64;
    float bv[4] = {0.f, 0.f, 0.f, 0.f};
    if (wave < 2) {
        #pragma unroll
        for (int ntl = 0; ntl < 4; ++ntl) bv[ntl] = b_att[cw + ntl * 16 + n15];
    }

    // Pack fp8 into this wave's private LDS slice (no barrier needed:
    // produced and consumed by the same wave; compiler emits lgkmcnt).
    #pragma unroll
    for (int ntl = 0; ntl < 4; ++ntl) {
        const int lc = ntl * 16 + n15;
        #pragma unroll
        for (int i = 0; i < 4; ++i)
            sP[wave][quad * 4 + i][lc] = f2fp8(acc[ntl][i] + bv[ntl]);
    }

    // Coalesced store: lane -> (row = lane>>2, 16B chunk = lane&3).
    unsigned char* Pt = (wave < 2) ? P1 : P2;
    const int cofs = (wave < 2) ? cw : cw - 128;
    const int lr = lane >> 2, ch = lane & 3;
    const uint4v pk = *(const uint4v*)&sP[wave][lr][ch * 16];
    *(uint4v*)(Pt + (size_t)(R + lr) * 128 + cofs + ch * 16) = pk;
}

// ---------------------------------------------------------------------------
// Kernel B: 16 lanes per code, 4 codes per wave.  Lane owns 8 cols.
// Gathers: P1[leaf] 8B fp8, P2[anc] 8B fp8, Ebf[anc] 16B bf16.
// ---------------------------------------------------------------------------
__global__ __launch_bounds__(256) void attention_main(
    const unsigned char* __restrict__ P1, const unsigned char* __restrict__ P2,
    const ushort* __restrict__ Ebf,
    const float* __restrict__ v_att,
    const int*   __restrict__ leaves, const int* __restrict__ anc,
    float*       __restrict__ out)
{
    const int t = threadIdx.x;
    const int wave = t >> 6, lane = t & 63;
    const int sub = lane >> 4, l16 = lane & 15;
    const int n = blockIdx.x * 16 + wave * 4 + sub;    // 6250*16 = NCODES exact

    const float4 vva = *(const float4*)(v_att + l16 * 8);
    const float4 vvb = *(const float4*)(v_att + l16 * 8 + 4);

    // distributed index load: lane j=l16<8 -> leaf j, j>=8 -> anc j-8
    const int jj = l16 & 7;
    const int lidx = (l16 & 8) ? anc[n * 8 + jj] : leaves[n * 8 + jj];

    short8 em[NANC];
    float q[NANC];
    #pragma unroll
    for (int a = 0; a < NANC; ++a) {
        const int lf = __shfl(lidx, (sub << 4) + a);
        const int an = __shfl(lidx, (sub << 4) + 8 + a);
        const uint2 r1 = *(const uint2*)(P1 + (size_t)lf * 128 + l16 * 8);
        const uint2 r2 = *(const uint2*)(P2 + (size_t)an * 128 + l16 * 8);
        em[a] = *(const short8*)(Ebf + (size_t)an * 128 + l16 * 8);
        floatx2 pa, pb;
        float qp;
        pa = fp8pair<false>(r1.x); pb = fp8pair<false>(r2.x);
        qp  = tanh_fast(pa[0] + pb[0]) * vva.x;
        qp  = fmaf(tanh_fast(pa[1] + pb[1]), vva.y, qp);
        pa = fp8pair<true>(r1.x);  pb = fp8pair<true>(r2.x);
        qp  = fmaf(tanh_fast(pa[0] + pb[0]), vva.z, qp);
        qp  = fmaf(tanh_fast(pa[1] + pb[1]), vva.w, qp);
        pa = fp8pair<false>(r1.y); pb = fp8pair<false>(r2.y);
        qp  = fmaf(tanh_fast(pa[0] + pb[0]), vvb.x, qp);
        qp  = fmaf(tanh_fast(pa[1] + pb[1]), vvb.y, qp);
        pa = fp8pair<true>(r1.y);  pb = fp8pair<true>(r2.y);
        qp  = fmaf(tanh_fast(pa[0] + pb[0]), vvb.z, qp);
        qp  = fmaf(tanh_fast(pa[1] + pb[1]), vvb.w, qp);
        q[a] = qp;
    }

    // Folded reduction over 16 lanes: a-bit2<-l-bit3, bit1<-l-bit2, bit0<-l-bit1
    float r4[4];
    #pragma unroll
    for (int i = 0; i < 4; ++i) {
        const float keep = (l16 & 8) ? q[i + 4] : q[i];
        const float send = (l16 & 8) ? q[i]     : q[i + 4];
        r4[i] = keep + __shfl_xor(send, 8);
    }
    float s2[2];
    #pragma unroll
    for (int i = 0; i < 2; ++i) {
        const float keep = (l16 & 4) ? r4[i + 2] : r4[i];
        const float send = (l16 & 4) ? r4[i]     : r4[i + 2];
        s2[i] = keep + __shfl_xor(send, 4);
    }
    {
        const float keep = (l16 & 2) ? s2[1] : s2[0];
        const float send = (l16 & 2) ? s2[0] : s2[1];
        s2[0] = keep + __shfl_xor(send, 2);
    }
    float tq = s2[0] + __shfl_xor(s2[0], 1);   // lane holds q_total[A(l)]

    // distributed softmax over the 8 a-groups (lane bits 3,2,1)
    float m = tq;
    m = fmaxf(m, __shfl_xor(m, 8));
    m = fmaxf(m, __shfl_xor(m, 4));
    m = fmaxf(m, __shfl_xor(m, 2));
    const float e = __expf(tq - m);
    float s = e;
    s += __shfl_xor(s, 8); s += __shfl_xor(s, 4); s += __shfl_xor(s, 2);
    const float wl = e * __fdividef(1.0f, s);

    // broadcast the 8 weights to every lane
    float wa[NANC];
    {
        const float p  = __shfl_xor(wl, 2);
        const float w0 = (l16 & 2) ? p  : wl;   // a-bit0 = 0
        const float w1 = (l16 & 2) ? wl : p;    // a-bit0 = 1
        const float p0 = __shfl_xor(w0, 4), p1 = __shfl_xor(w1, 4);
        const float v00 = (l16 & 4) ? p0 : w0, v01 = (l16 & 4) ? p1 : w1;
        const float v10 = (l16 & 4) ? w0 : p0, v11 = (l16 & 4) ? w1 : p1;
        float g;
        g = __shfl_xor(v00, 8); wa[0] = (l16 & 8) ? g : v00; wa[4] = (l16 & 8) ? v00 : g;
        g = __shfl_xor(v01, 8); wa[1] = (l16 & 8) ? g : v01; wa[5] = (l16 & 8) ? v01 : g;
        g = __shfl_xor(v10, 8); wa[2] = (l16 & 8) ? g : v10; wa[6] = (l16 & 8) ? v10 : g;
        g = __shfl_xor(v11, 8); wa[3] = (l16 & 8) ? g : v11; wa[7] = (l16 & 8) ? v11 : g;
    }

    float o[8] = {0.f, 0.f, 0.f, 0.f, 0.f, 0.f, 0.f, 0.f};
    #pragma unroll
    for (int a = 0; a < NANC; ++a) {
        #pragma unroll
        for (int c = 0; c < 8; ++c)
            o[c] = fmaf(wa[a], bf2f((ushort)em[a][c]), o[c]);
    }
    float4v o1, o2;
    o1[0] = o[0]; o1[1] = o[1]; o1[2] = o[2]; o1[3] = o[3];
    o2[0] = o[4]; o2[1] = o[5]; o2[2] = o[6]; o2[3] = o[7];
    __builtin_nontemporal_store(o1, (float4v*)(out + (size_t)n * 128 + l16 * 8));
    __builtin_nontemporal_store(o2, (float4v*)(out + (size_t)n * 128 + l16 * 8 + 4));
}

// ---------------------------------------------------------------------------
extern "C" void kernel_launch(void* const* d_in, const int* in_sizes, int n_in,
                              void* d_out, int out_size, void* d_ws, size_t ws_size,
                              hipStream_t stream) {
    const float* W_emb  = (const float*)d_in[0];
    const float* W_att  = (const float*)d_in[1];
    const float* b_att  = (const float*)d_in[2];
    const float* v_att  = (const float*)d_in[3];
    const int*   leaves = (const int*)d_in[4];
    const int*   anc    = (const int*)d_in[5];
    float*       out    = (float*)d_out;

    unsigned char* P1 = (unsigned char*)d_ws;            // 12.8 MB fp8
    unsigned char* P2 = P1 + (size_t)VOCAB * 128;        // 12.8 MB fp8
    ushort* Ebf = (ushort*)(P2 + (size_t)VOCAB * 128);   // 25.6 MB bf16
    ushort* WT  = Ebf + (size_t)VOCAB * 128;             // 64 KB bf16

    transpose_watt<<<128, 256, 0, stream>>>(W_att, WT);
    precompute<<<VOCAB / 16, 256, 0, stream>>>(W_emb, WT, b_att, P1, P2, Ebf);
    attention_main<<<NCODES / 16, 256, 0, stream>>>(P1, P2, Ebf, v_att,
                                                    leaves, anc, out);
}

// Round 6
// 218.354 us; speedup vs baseline: 1.1135x; 1.0578x over previous
//
#include <hip/hip_runtime.h>
#include <hip/hip_bf16.h>
#include <hip/hip_fp8.h>

#define VOCAB  100000
#define EMB    128
#define NCODES 100000
#define NANC   8

typedef __attribute__((ext_vector_type(8))) short  short8;
typedef __attribute__((ext_vector_type(4))) float  float4v;
typedef __attribute__((ext_vector_type(2))) float  floatx2;

__device__ __forceinline__ ushort f2bf(float x) {     // RNE f32 -> bf16 bits
    unsigned u = __float_as_uint(x);
    u += 0x7fffu + ((u >> 16) & 1u);
    return (ushort)(u >> 16);
}
__device__ __forceinline__ float bf2f(ushort h) {
    return __uint_as_float((unsigned)h << 16);
}
__device__ __forceinline__ float tanh_fast(float x) {
    float e = __expf(2.0f * x);               // saturates correctly at +-inf
    return 1.0f - __fdividef(2.0f, e + 1.0f);
}
__device__ __forceinline__ unsigned char f2fp8(float x) {  // OCP e4m3, RNE+sat
    __hip_fp8_e4m3 t(x);
    return t.__x;
}
// pack 4 f32 -> 4 fp8 bytes in one dword (byte i = v[i], little-endian)
__device__ __forceinline__ unsigned pack_fp8x4(float a, float b, float c, float d) {
#if __has_builtin(__builtin_amdgcn_cvt_pk_fp8_f32)
    int w = __builtin_amdgcn_cvt_pk_fp8_f32(a, b, 0, false);   // bytes 0,1
    w = __builtin_amdgcn_cvt_pk_fp8_f32(c, d, w, true);        // bytes 2,3
    return (unsigned)w;
#else
    return (unsigned)f2fp8(a) | ((unsigned)f2fp8(b) << 8)
         | ((unsigned)f2fp8(c) << 16) | ((unsigned)f2fp8(d) << 24);
#endif
}
// decode 2 fp8 from the low/high 16-bit word of v (HI must be compile-time)
template <bool HI>
__device__ __forceinline__ floatx2 fp8pair(unsigned v) {
#if __has_builtin(__builtin_amdgcn_cvt_pk_f32_fp8)
    return __builtin_amdgcn_cvt_pk_f32_fp8((int)v, HI);
#else
    __hip_fp8_e4m3 a, b;
    const unsigned s = HI ? 16u : 0u;
    a.__x = (v >> s) & 0xffu;
    b.__x = (v >> (s + 8u)) & 0xffu;
    floatx2 r; r[0] = (float)a; r[1] = (float)b; return r;
#endif
}

// ---------------------------------------------------------------------------
// Kernel A0: WT[c][e] = bf16(W_att[h*128+e][d]), c = h*128+d.  64 KB output.
// ---------------------------------------------------------------------------
__global__ void transpose_watt(const float* __restrict__ W_att,
                               ushort* __restrict__ WT)
{
    const int id = blockIdx.x * 256 + threadIdx.x;   // 32768 total
    const int c = id >> 7, e = id & 127;
    const int h = c >> 7, d = c & 127;
    WT[c * 128 + e] = f2bf(W_att[(h * 128 + e) * 128 + d]);
}

// ---------------------------------------------------------------------------
// Kernel A: MFMA precompute with SWAPPED operands: D = WTfrag . Wembfrag
// => D[m=outcol][n=vocabrow]; C/D layout col=lane&15 -> vocab row,
// row=quad*4+reg -> output col. So each lane's 4 acc regs are 4 CONSECUTIVE
// output columns of one vocab row: pack to one fp8 dword, store directly.
// No LDS, no bank conflicts, bias via one float4 load. Grid-stride loop:
// WT fragments (A-operand) are loaded once per block, reused for all tiles;
// independent tiles let the compiler software-pipeline load vs MFMA.
// ---------------------------------------------------------------------------
__global__ __launch_bounds__(256) void precompute(
    const float*  __restrict__ W_emb,   // [VOCAB][128] f32
    const ushort* __restrict__ WT,      // [256][128] bf16 (A0 output)
    const float*  __restrict__ b_att,   // [128]
    unsigned char* __restrict__ P1,     // [VOCAB][128] fp8
    unsigned char* __restrict__ P2,     // [VOCAB][128] fp8
    ushort*        __restrict__ Ebf)    // [VOCAB][128] bf16
{
    const int t = threadIdx.x, wave = t >> 6, lane = t & 63;
    const int n15 = lane & 15, quad = lane >> 4;
    const int cw = wave * 64;                      // this wave's 64 output cols

    // A-operand frags (m = output col): A[m][k] = WT[cw+ntl*16+n15][k]
    short8 wfrag[4][4];                            // [kt][ntl]
    #pragma unroll
    for (int ntl = 0; ntl < 4; ++ntl) {
        const int c = cw + ntl * 16 + n15;
        #pragma unroll
        for (int kt = 0; kt < 4; ++kt)
            wfrag[kt][ntl] = *(const short8*)(WT + c * 128 + kt * 32 + quad * 8);
    }

    // bias: cols cw + ntl*16 + quad*4 .. +3 (P1 waves only; fold into store)
    float4 bb[4];
    #pragma unroll
    for (int ntl = 0; ntl < 4; ++ntl) {
        if (wave < 2) bb[ntl] = *(const float4*)(b_att + cw + ntl * 16 + quad * 4);
        else          bb[ntl] = make_float4(0.f, 0.f, 0.f, 0.f);
    }

    unsigned char* Pt = (wave < 2) ? P1 : P2;
    const int cofs = ((wave < 2) ? cw : cw - 128) + quad * 4;

    for (int rt = blockIdx.x; rt < VOCAB / 16; rt += gridDim.x) {
        const int R = rt * 16;
        float4v acc[4];
        #pragma unroll
        for (int i = 0; i < 4; ++i) acc[i] = (float4v)0.0f;

        #pragma unroll
        for (int kt = 0; kt < 4; ++kt) {
            // B-operand frag (n = vocab row): B[k][n] = W_emb[R+n15][k]
            const float4* src = (const float4*)(W_emb + (size_t)(R + n15) * 128
                                                + kt * 32 + quad * 8);
            const float4 a0 = src[0], a1 = src[1];
            short8 af;
            af[0] = f2bf(a0.x); af[1] = f2bf(a0.y); af[2] = f2bf(a0.z); af[3] = f2bf(a0.w);
            af[4] = f2bf(a1.x); af[5] = f2bf(a1.y); af[6] = f2bf(a1.z); af[7] = f2bf(a1.w);
            if (wave == 0)    // bf16 W_emb copy (all waves load same rows)
                *(short8*)(Ebf + (size_t)(R + n15) * 128 + kt * 32 + quad * 8) = af;
            #pragma unroll
            for (int ntl = 0; ntl < 4; ++ntl)
                acc[ntl] = __builtin_amdgcn_mfma_f32_16x16x32_bf16(
                               wfrag[kt][ntl], af, acc[ntl], 0, 0, 0);
        }

        // Epilogue: lane owns vocab row R+n15, cols cofs+ntl*16 .. +3 -> dword
        #pragma unroll
        for (int ntl = 0; ntl < 4; ++ntl) {
            const unsigned pk = pack_fp8x4(acc[ntl][0] + bb[ntl].x,
                                           acc[ntl][1] + bb[ntl].y,
                                           acc[ntl][2] + bb[ntl].z,
                                           acc[ntl][3] + bb[ntl].w);
            *(unsigned*)(Pt + (size_t)(R + n15) * 128 + cofs + ntl * 16) = pk;
        }
    }
}

// ---------------------------------------------------------------------------
// Kernel B: 16 lanes per code, 4 codes per wave.  Lane owns 8 cols.
// All 24 gathers hoisted ahead of compute (load-level parallelism).
// ---------------------------------------------------------------------------
__global__ __launch_bounds__(256) void attention_main(
    const unsigned char* __restrict__ P1, const unsigned char* __restrict__ P2,
    const ushort* __restrict__ Ebf,
    const float* __restrict__ v_att,
    const int*   __restrict__ leaves, const int* __restrict__ anc,
    float*       __restrict__ out)
{
    const int t = threadIdx.x;
    const int wave = t >> 6, lane = t & 63;
    const int sub = lane >> 4, l16 = lane & 15;
    const int n = blockIdx.x * 16 + wave * 4 + sub;    // 6250*16 = NCODES exact

    const float4 vva = *(const float4*)(v_att + l16 * 8);
    const float4 vvb = *(const float4*)(v_att + l16 * 8 + 4);

    // distributed index load: lane j=l16<8 -> leaf j, j>=8 -> anc j-8
    const int jj = l16 & 7;
    const int lidx = (l16 & 8) ? anc[n * 8 + jj] : leaves[n * 8 + jj];

    int lf[NANC], an[NANC];
    #pragma unroll
    for (int a = 0; a < NANC; ++a) {
        lf[a] = __shfl(lidx, (sub << 4) + a);
        an[a] = __shfl(lidx, (sub << 4) + 8 + a);
    }

    // hoisted gathers: 24 loads in flight
    uint2 r1[NANC], r2[NANC];
    short8 em[NANC];
    #pragma unroll
    for (int a = 0; a < NANC; ++a)
        r1[a] = *(const uint2*)(P1 + (size_t)lf[a] * 128 + l16 * 8);
    #pragma unroll
    for (int a = 0; a < NANC; ++a)
        r2[a] = *(const uint2*)(P2 + (size_t)an[a] * 128 + l16 * 8);
    #pragma unroll
    for (int a = 0; a < NANC; ++a)
        em[a] = *(const short8*)(Ebf + (size_t)an[a] * 128 + l16 * 8);

    float q[NANC];
    #pragma unroll
    for (int a = 0; a < NANC; ++a) {
        floatx2 pa, pb;
        float qp;
        pa = fp8pair<false>(r1[a].x); pb = fp8pair<false>(r2[a].x);
        qp  = tanh_fast(pa[0] + pb[0]) * vva.x;
        qp  = fmaf(tanh_fast(pa[1] + pb[1]), vva.y, qp);
        pa = fp8pair<true>(r1[a].x);  pb = fp8pair<true>(r2[a].x);
        qp  = fmaf(tanh_fast(pa[0] + pb[0]), vva.z, qp);
        qp  = fmaf(tanh_fast(pa[1] + pb[1]), vva.w, qp);
        pa = fp8pair<false>(r1[a].y); pb = fp8pair<false>(r2[a].y);
        qp  = fmaf(tanh_fast(pa[0] + pb[0]), vvb.x, qp);
        qp  = fmaf(tanh_fast(pa[1] + pb[1]), vvb.y, qp);
        pa = fp8pair<true>(r1[a].y);  pb = fp8pair<true>(r2[a].y);
        qp  = fmaf(tanh_fast(pa[0] + pb[0]), vvb.z, qp);
        qp  = fmaf(tanh_fast(pa[1] + pb[1]), vvb.w, qp);
        q[a] = qp;
    }

    // Folded reduction over 16 lanes: a-bit2<-l-bit3, bit1<-l-bit2, bit0<-l-bit1
    float r4[4];
    #pragma unroll
    for (int i = 0; i < 4; ++i) {
        const float keep = (l16 & 8) ? q[i + 4] : q[i];
        const float send = (l16 & 8) ? q[i]     : q[i + 4];
        r4[i] = keep + __shfl_xor(send, 8);
    }
    float s2[2];
    #pragma unroll
    for (int i = 0; i < 2; ++i) {
        const float keep = (l16 & 4) ? r4[i + 2] : r4[i];
        const float send = (l16 & 4) ? r4[i]     : r4[i + 2];
        s2[i] = keep + __shfl_xor(send, 4);
    }
    {
        const float keep = (l16 & 2) ? s2[1] : s2[0];
        const float send = (l16 & 2) ? s2[0] : s2[1];
        s2[0] = keep + __shfl_xor(send, 2);
    }
    float tq = s2[0] + __shfl_xor(s2[0], 1);   // lane holds q_total[A(l)]

    // distributed softmax over the 8 a-groups (lane bits 3,2,1)
    float m = tq;
    m = fmaxf(m, __shfl_xor(m, 8));
    m = fmaxf(m, __shfl_xor(m, 4));
    m = fmaxf(m, __shfl_xor(m, 2));
    const float e = __expf(tq - m);
    float s = e;
    s += __shfl_xor(s, 8); s += __shfl_xor(s, 4); s += __shfl_xor(s, 2);
    const float wl = e * __fdividef(1.0f, s);

    // broadcast the 8 weights to every lane
    float wa[NANC];
    {
        const float p  = __shfl_xor(wl, 2);
        const float w0 = (l16 & 2) ? p  : wl;   // a-bit0 = 0
        const float w1 = (l16 & 2) ? wl : p;    // a-bit0 = 1
        const float p0 = __shfl_xor(w0, 4), p1 = __shfl_xor(w1, 4);
        const float v00 = (l16 & 4) ? p0 : w0, v01 = (l16 & 4) ? p1 : w1;
        const float v10 = (l16 & 4) ? w0 : p0, v11 = (l16 & 4) ? w1 : p1;
        float g;
        g = __shfl_xor(v00, 8); wa[0] = (l16 & 8) ? g : v00; wa[4] = (l16 & 8) ? v00 : g;
        g = __shfl_xor(v01, 8); wa[1] = (l16 & 8) ? g : v01; wa[5] = (l16 & 8) ? v01 : g;
        g = __shfl_xor(v10, 8); wa[2] = (l16 & 8) ? g : v10; wa[6] = (l16 & 8) ? v10 : g;
        g = __shfl_xor(v11, 8); wa[3] = (l16 & 8) ? g : v11; wa[7] = (l16 & 8) ? v11 : g;
    }

    float o[8] = {0.f, 0.f, 0.f, 0.f, 0.f, 0.f, 0.f, 0.f};
    #pragma unroll
    for (int a = 0; a < NANC; ++a) {
        #pragma unroll
        for (int c = 0; c < 8; ++c)
            o[c] = fmaf(wa[a], bf2f((ushort)em[a][c]), o[c]);
    }
    float4v o1, o2;
    o1[0] = o[0]; o1[1] = o[1]; o1[2] = o[2]; o1[3] = o[3];
    o2[0] = o[4]; o2[1] = o[5]; o2[2] = o[6]; o2[3] = o[7];
    __builtin_nontemporal_store(o1, (float4v*)(out + (size_t)n * 128 + l16 * 8));
    __builtin_nontemporal_store(o2, (float4v*)(out + (size_t)n * 128 + l16 * 8 + 4));
}

// ---------------------------------------------------------------------------
extern "C" void kernel_launch(void* const* d_in, const int* in_sizes, int n_in,
                              void* d_out, int out_size, void* d_ws, size_t ws_size,
                              hipStream_t stream) {
    const float* W_emb  = (const float*)d_in[0];
    const float* W_att  = (const float*)d_in[1];
    const float* b_att  = (const float*)d_in[2];
    const float* v_att  = (const float*)d_in[3];
    const int*   leaves = (const int*)d_in[4];
    const int*   anc    = (const int*)d_in[5];
    float*       out    = (float*)d_out;

    unsigned char* P1 = (unsigned char*)d_ws;            // 12.8 MB fp8
    unsigned char* P2 = P1 + (size_t)VOCAB * 128;        // 12.8 MB fp8
    ushort* Ebf = (ushort*)(P2 + (size_t)VOCAB * 128);   // 25.6 MB bf16
    ushort* WT  = Ebf + (size_t)VOCAB * 128;             // 64 KB bf16

    transpose_watt<<<128, 256, 0, stream>>>(W_att, WT);
    precompute<<<1250, 256, 0, stream>>>(W_emb, WT, b_att, P1, P2, Ebf);
    attention_main<<<NCODES / 16, 256, 0, stream>>>(P1, P2, Ebf, v_att,
                                                    leaves, anc, out);
}

// Round 7
// 199.606 us; speedup vs baseline: 1.2181x; 1.0939x over previous
//
#include <hip/hip_runtime.h>
#include <hip/hip_bf16.h>
#include <hip/hip_fp8.h>

#define VOCAB  100000
#define EMB    128
#define NCODES 100000
#define NANC   8

typedef __attribute__((ext_vector_type(8))) short  short8;
typedef __attribute__((ext_vector_type(4))) float  float4v;
typedef __attribute__((ext_vector_type(2))) float  floatx2;

__device__ __forceinline__ ushort f2bf(float x) {     // RNE f32 -> bf16 bits
    unsigned u = __float_as_uint(x);
    u += 0x7fffu + ((u >> 16) & 1u);
    return (ushort)(u >> 16);
}
__device__ __forceinline__ float bf2f(ushort h) {
    return __uint_as_float((unsigned)h << 16);
}
__device__ __forceinline__ unsigned char f2fp8(float x) {  // OCP e4m3, RNE+sat
    __hip_fp8_e4m3 t(x);
    return t.__x;
}
// pack 4 f32 -> 4 fp8 bytes in one dword (byte i = v[i], little-endian)
__device__ __forceinline__ unsigned pack_fp8x4(float a, float b, float c, float d) {
#if __has_builtin(__builtin_amdgcn_cvt_pk_fp8_f32)
    int w = __builtin_amdgcn_cvt_pk_fp8_f32(a, b, 0, false);   // bytes 0,1
    w = __builtin_amdgcn_cvt_pk_fp8_f32(c, d, w, true);        // bytes 2,3
    return (unsigned)w;
#else
    return (unsigned)f2fp8(a) | ((unsigned)f2fp8(b) << 8)
         | ((unsigned)f2fp8(c) << 16) | ((unsigned)f2fp8(d) << 24);
#endif
}
// decode 2 fp8 from the low/high 16-bit word of v (HI must be compile-time)
template <bool HI>
__device__ __forceinline__ floatx2 fp8pair(unsigned v) {
#if __has_builtin(__builtin_amdgcn_cvt_pk_f32_fp8)
    return __builtin_amdgcn_cvt_pk_f32_fp8((int)v, HI);
#else
    __hip_fp8_e4m3 a, b;
    const unsigned s = HI ? 16u : 0u;
    a.__x = (v >> s) & 0xffu;
    b.__x = (v >> (s + 8u)) & 0xffu;
    floatx2 r; r[0] = (float)a; r[1] = (float)b; return r;
#endif
}

// Packed-f32 tanh for 2 float2 pairs (4 elems), one v_rcp total.
// tanh(x) ~= x(945+105y+y^2)/(945+420y+15y^2), y=x^2 (continued-fraction
// Pade, exact integer coeffs; |err|<~5e-4 on [-3.5,3.5]). Clamp +-3.5;
// saturation error <= 1.8e-3 (true tanh in [0.99818,1) vs 0.99924).
__device__ __forceinline__ void tanh2pk(floatx2 za, floatx2 zb,
                                        floatx2& ta, floatx2& tb) {
    floatx2 xa, xb;
    xa[0] = fminf(fmaxf(za[0], -3.5f), 3.5f);   // v_med3_f32
    xa[1] = fminf(fmaxf(za[1], -3.5f), 3.5f);
    xb[0] = fminf(fmaxf(zb[0], -3.5f), 3.5f);
    xb[1] = fminf(fmaxf(zb[1], -3.5f), 3.5f);
    const floatx2 ya = xa * xa, yb = xb * xb;
    floatx2 Na = ya + 105.0f;  Na = ya * Na + 945.0f;       // y^2+105y+945
    floatx2 Nb = yb + 105.0f;  Nb = yb * Nb + 945.0f;
    floatx2 Da = ya * 15.0f + 420.0f;  Da = ya * Da + 945.0f; // 15y^2+420y+945
    floatx2 Db = yb * 15.0f + 420.0f;  Db = yb * Db + 945.0f;
    const floatx2 Dp = Da * Db;
    const float r = __builtin_amdgcn_rcpf(Dp[0] * Dp[1]);   // 1/(prod of 4 D)
    floatx2 qv;  qv[0] = r * Dp[1];  qv[1] = r * Dp[0];
    const floatx2 ia = qv * Db;      // (1/Da0, 1/Da1)
    const floatx2 ib = qv * Da;      // (1/Db0, 1/Db1)
    ta = (xa * Na) * ia;
    tb = (xb * Nb) * ib;
}

// ---------------------------------------------------------------------------
// Kernel A0: WT[c][e] = bf16(W_att[h*128+e][d]), c = h*128+d.  64 KB output.
// ---------------------------------------------------------------------------
__global__ void transpose_watt(const float* __restrict__ W_att,
                               ushort* __restrict__ WT)
{
    const int id = blockIdx.x * 256 + threadIdx.x;   // 32768 total
    const int c = id >> 7, e = id & 127;
    const int h = c >> 7, d = c & 127;
    WT[c * 128 + e] = f2bf(W_att[(h * 128 + e) * 128 + d]);
}

// ---------------------------------------------------------------------------
// Kernel A: MFMA precompute, swapped operands (D = WT . Wemb => lane owns one
// vocab row, 4 consecutive out cols per acc reg -> direct fp8 dword store).
// Grid-stride with EXPLICIT next-tile prefetch: the 8 W_emb loads of tile
// t+1 are issued before tile t's cvt+MFMA+store chain (latency hiding).
// ---------------------------------------------------------------------------
__global__ __launch_bounds__(256) void precompute(
    const float*  __restrict__ W_emb,   // [VOCAB][128] f32
    const ushort* __restrict__ WT,      // [256][128] bf16 (A0 output)
    const float*  __restrict__ b_att,   // [128]
    unsigned char* __restrict__ P1,     // [VOCAB][128] fp8
    unsigned char* __restrict__ P2,     // [VOCAB][128] fp8
    ushort*        __restrict__ Ebf)    // [VOCAB][128] bf16
{
    const int t = threadIdx.x, wave = t >> 6, lane = t & 63;
    const int n15 = lane & 15, quad = lane >> 4;
    const int cw = wave * 64;                      // this wave's 64 output cols

    // A-operand frags (m = output col): A[m][k] = WT[cw+ntl*16+n15][k]
    short8 wfrag[4][4];                            // [kt][ntl]
    #pragma unroll
    for (int ntl = 0; ntl < 4; ++ntl) {
        const int c = cw + ntl * 16 + n15;
        #pragma unroll
        for (int kt = 0; kt < 4; ++kt)
            wfrag[kt][ntl] = *(const short8*)(WT + c * 128 + kt * 32 + quad * 8);
    }

    // bias: cols cw + ntl*16 + quad*4 .. +3 (P1 waves only; fold into store)
    float4 bb[4];
    #pragma unroll
    for (int ntl = 0; ntl < 4; ++ntl) {
        if (wave < 2) bb[ntl] = *(const float4*)(b_att + cw + ntl * 16 + quad * 4);
        else          bb[ntl] = make_float4(0.f, 0.f, 0.f, 0.f);
    }

    unsigned char* Pt = (wave < 2) ? P1 : P2;
    const int cofs = ((wave < 2) ? cw : cw - 128) + quad * 4;

    const int NT = VOCAB / 16;
    int rt = blockIdx.x;
    float4 cur[8];
    {   // load first tile
        const float4* src = (const float4*)(W_emb + (size_t)(rt * 16 + n15) * 128);
        #pragma unroll
        for (int kt = 0; kt < 4; ++kt) {
            cur[2 * kt]     = src[kt * 8 + quad * 2];
            cur[2 * kt + 1] = src[kt * 8 + quad * 2 + 1];
        }
    }

    for (; rt < NT; ) {
        const int nrt = rt + gridDim.x;
        float4 nxt[8];
        if (nrt < NT) {     // prefetch next tile's rows while computing cur
            const float4* src = (const float4*)(W_emb + (size_t)(nrt * 16 + n15) * 128);
            #pragma unroll
            for (int kt = 0; kt < 4; ++kt) {
                nxt[2 * kt]     = src[kt * 8 + quad * 2];
                nxt[2 * kt + 1] = src[kt * 8 + quad * 2 + 1];
            }
        }

        const int R = rt * 16;
        float4v acc[4];
        #pragma unroll
        for (int i = 0; i < 4; ++i) acc[i] = (float4v)0.0f;

        #pragma unroll
        for (int kt = 0; kt < 4; ++kt) {
            const float4 a0 = cur[2 * kt], a1 = cur[2 * kt + 1];
            short8 af;
            af[0] = f2bf(a0.x); af[1] = f2bf(a0.y); af[2] = f2bf(a0.z); af[3] = f2bf(a0.w);
            af[4] = f2bf(a1.x); af[5] = f2bf(a1.y); af[6] = f2bf(a1.z); af[7] = f2bf(a1.w);
            if (wave == 0)    // bf16 W_emb copy
                *(short8*)(Ebf + (size_t)(R + n15) * 128 + kt * 32 + quad * 8) = af;
            #pragma unroll
            for (int ntl = 0; ntl < 4; ++ntl)
                acc[ntl] = __builtin_amdgcn_mfma_f32_16x16x32_bf16(
                               wfrag[kt][ntl], af, acc[ntl], 0, 0, 0);
        }

        // Epilogue: lane owns vocab row R+n15, cols cofs+ntl*16 .. +3 -> dword
        #pragma unroll
        for (int ntl = 0; ntl < 4; ++ntl) {
            const unsigned pk = pack_fp8x4(acc[ntl][0] + bb[ntl].x,
                                           acc[ntl][1] + bb[ntl].y,
                                           acc[ntl][2] + bb[ntl].z,
                                           acc[ntl][3] + bb[ntl].w);
            *(unsigned*)(Pt + (size_t)(R + n15) * 128 + cofs + ntl * 16) = pk;
        }

        rt = nrt;
        #pragma unroll
        for (int i = 0; i < 8; ++i) cur[i] = nxt[i];
    }
}

// ---------------------------------------------------------------------------
// Kernel B: 16 lanes per code, 4 codes per wave.  Lane owns 8 cols.
// Hoisted gathers; packed-f32 Pade tanh (1 transcendental per 4 elems).
// ---------------------------------------------------------------------------
__global__ __launch_bounds__(256) void attention_main(
    const unsigned char* __restrict__ P1, const unsigned char* __restrict__ P2,
    const ushort* __restrict__ Ebf,
    const float* __restrict__ v_att,
    const int*   __restrict__ leaves, const int* __restrict__ anc,
    float*       __restrict__ out)
{
    const int t = threadIdx.x;
    const int wave = t >> 6, lane = t & 63;
    const int sub = lane >> 4, l16 = lane & 15;
    const int n = blockIdx.x * 16 + wave * 4 + sub;    // 6250*16 = NCODES exact

    floatx2 vv[4];
    #pragma unroll
    for (int p = 0; p < 4; ++p)
        vv[p] = *(const floatx2*)(v_att + l16 * 8 + 2 * p);

    // distributed index load: lane j=l16<8 -> leaf j, j>=8 -> anc j-8
    const int jj = l16 & 7;
    const int lidx = (l16 & 8) ? anc[n * 8 + jj] : leaves[n * 8 + jj];

    int lf[NANC], an[NANC];
    #pragma unroll
    for (int a = 0; a < NANC; ++a) {
        lf[a] = __shfl(lidx, (sub << 4) + a);
        an[a] = __shfl(lidx, (sub << 4) + 8 + a);
    }

    // hoisted gathers: 24 loads in flight
    uint2 r1[NANC], r2[NANC];
    short8 em[NANC];
    #pragma unroll
    for (int a = 0; a < NANC; ++a)
        r1[a] = *(const uint2*)(P1 + (size_t)lf[a] * 128 + l16 * 8);
    #pragma unroll
    for (int a = 0; a < NANC; ++a)
        r2[a] = *(const uint2*)(P2 + (size_t)an[a] * 128 + l16 * 8);
    #pragma unroll
    for (int a = 0; a < NANC; ++a)
        em[a] = *(const short8*)(Ebf + (size_t)an[a] * 128 + l16 * 8);

    float q[NANC];
    #pragma unroll
    for (int a = 0; a < NANC; ++a) {
        const floatx2 z0 = fp8pair<false>(r1[a].x) + fp8pair<false>(r2[a].x);
        const floatx2 z1 = fp8pair<true >(r1[a].x) + fp8pair<true >(r2[a].x);
        const floatx2 z2 = fp8pair<false>(r1[a].y) + fp8pair<false>(r2[a].y);
        const floatx2 z3 = fp8pair<true >(r1[a].y) + fp8pair<true >(r2[a].y);
        floatx2 t0, t1, t2, t3;
        tanh2pk(z0, z1, t0, t1);
        tanh2pk(z2, z3, t2, t3);
        floatx2 qa = t0 * vv[0];
        qa = t1 * vv[1] + qa;
        qa = t2 * vv[2] + qa;
        qa = t3 * vv[3] + qa;
        q[a] = qa[0] + qa[1];
    }

    // Folded reduction over 16 lanes: a-bit2<-l-bit3, bit1<-l-bit2, bit0<-l-bit1
    float r4[4];
    #pragma unroll
    for (int i = 0; i < 4; ++i) {
        const float keep = (l16 & 8) ? q[i + 4] : q[i];
        const float send = (l16 & 8) ? q[i]     : q[i + 4];
        r4[i] = keep + __shfl_xor(send, 8);
    }
    float s2[2];
    #pragma unroll
    for (int i = 0; i < 2; ++i) {
        const float keep = (l16 & 4) ? r4[i + 2] : r4[i];
        const float send = (l16 & 4) ? r4[i]     : r4[i + 2];
        s2[i] = keep + __shfl_xor(send, 4);
    }
    {
        const float keep = (l16 & 2) ? s2[1] : s2[0];
        const float send = (l16 & 2) ? s2[0] : s2[1];
        s2[0] = keep + __shfl_xor(send, 2);
    }
    float tq = s2[0] + __shfl_xor(s2[0], 1);   // lane holds q_total[A(l)]

    // distributed softmax over the 8 a-groups (lane bits 3,2,1)
    float m = tq;
    m = fmaxf(m, __shfl_xor(m, 8));
    m = fmaxf(m, __shfl_xor(m, 4));
    m = fmaxf(m, __shfl_xor(m, 2));
    const float e = __expf(tq - m);
    float s = e;
    s += __shfl_xor(s, 8); s += __shfl_xor(s, 4); s += __shfl_xor(s, 2);
    const float wl = e * __fdividef(1.0f, s);

    // broadcast the 8 weights to every lane
    float wa[NANC];
    {
        const float p  = __shfl_xor(wl, 2);
        const float w0 = (l16 & 2) ? p  : wl;   // a-bit0 = 0
        const float w1 = (l16 & 2) ? wl : p;    // a-bit0 = 1
        const float p0 = __shfl_xor(w0, 4), p1 = __shfl_xor(w1, 4);
        const float v00 = (l16 & 4) ? p0 : w0, v01 = (l16 & 4) ? p1 : w1;
        const float v10 = (l16 & 4) ? w0 : p0, v11 = (l16 & 4) ? w1 : p1;
        float g;
        g = __shfl_xor(v00, 8); wa[0] = (l16 & 8) ? g : v00; wa[4] = (l16 & 8) ? v00 : g;
        g = __shfl_xor(v01, 8); wa[1] = (l16 & 8) ? g : v01; wa[5] = (l16 & 8) ? v01 : g;
        g = __shfl_xor(v10, 8); wa[2] = (l16 & 8) ? g : v10; wa[6] = (l16 & 8) ? v10 : g;
        g = __shfl_xor(v11, 8); wa[3] = (l16 & 8) ? g : v11; wa[7] = (l16 & 8) ? v11 : g;
    }

    // weighted sum, packed f32 over col pairs
    floatx2 o[4] = {(floatx2)0.f, (floatx2)0.f, (floatx2)0.f, (floatx2)0.f};
    #pragma unroll
    for (int a = 0; a < NANC; ++a) {
        floatx2 wv; wv[0] = wa[a]; wv[1] = wa[a];
        #pragma unroll
        for (int p = 0; p < 4; ++p) {
            floatx2 ev;
            ev[0] = bf2f((ushort)em[a][2 * p]);
            ev[1] = bf2f((ushort)em[a][2 * p + 1]);
            o[p] = ev * wv + o[p];
        }
    }
    float4v o1, o2;
    o1[0] = o[0][0]; o1[1] = o[0][1]; o1[2] = o[1][0]; o1[3] = o[1][1];
    o2[0] = o[2][0]; o2[1] = o[2][1]; o2[2] = o[3][0]; o2[3] = o[3][1];
    __builtin_nontemporal_store(o1, (float4v*)(out + (size_t)n * 128 + l16 * 8));
    __builtin_nontemporal_store(o2, (float4v*)(out + (size_t)n * 128 + l16 * 8 + 4));
}

// ---------------------------------------------------------------------------
extern "C" void kernel_launch(void* const* d_in, const int* in_sizes, int n_in,
                              void* d_out, int out_size, void* d_ws, size_t ws_size,
                              hipStream_t stream) {
    const float* W_emb  = (const float*)d_in[0];
    const float* W_att  = (const float*)d_in[1];
    const float* b_att  = (const float*)d_in[2];
    const float* v_att  = (const float*)d_in[3];
    const int*   leaves = (const int*)d_in[4];
    const int*   anc    = (const int*)d_in[5];
    float*       out    = (float*)d_out;

    unsigned char* P1 = (unsigned char*)d_ws;            // 12.8 MB fp8
    unsigned char* P2 = P1 + (size_t)VOCAB * 128;        // 12.8 MB fp8
    ushort* Ebf = (ushort*)(P2 + (size_t)VOCAB * 128);   // 25.6 MB bf16
    ushort* WT  = Ebf + (size_t)VOCAB * 128;             // 64 KB bf16

    transpose_watt<<<128, 256, 0, stream>>>(W_att, WT);
    precompute<<<1250, 256, 0, stream>>>(W_emb, WT, b_att, P1, P2, Ebf);
    attention_main<<<NCODES / 16, 256, 0, stream>>>(P1, P2, Ebf, v_att,
                                                    leaves, anc, out);
}